// Round 7
// baseline (2691.066 us; speedup 1.0000x reference)
//
#include <hip/hip_runtime.h>
#include <hip/hip_bf16.h>
#include <stdio.h>

typedef unsigned short u16;
typedef unsigned int u32;

#define N_PTS 16384
#define N_GRID 4096
#define GPTS 512
#define HD 128
#define DEG 16

__device__ __forceinline__ float b2f(u16 u) { return __uint_as_float(((u32)u) << 16); }
__device__ __forceinline__ float silu_f(float x) { return x / (1.0f + expf(-x)); }

__device__ __forceinline__ float blockReduce128(float v, volatile float* s) {
#pragma unroll
    for (int o = 32; o > 0; o >>= 1) v += __shfl_down(v, o, 64);
    __syncthreads();
    if ((threadIdx.x & 63) == 0) s[threadIdx.x >> 6] = v;
    __syncthreads();
    return s[0] + s[1];
}

__global__ void k_fillf(float* out, float v, int n) {
    int i = blockIdx.x * blockDim.x + threadIdx.x;
    if (i < n) out[i] = v;
}

// ---------------- init: x_q = qp, h_g = codes, h_q = 0 ----------------
__global__ void k_init(const float* __restrict__ qp, const float* __restrict__ codes,
                       float* __restrict__ x_q, float* __restrict__ h_g, float* __restrict__ h_q) {
    int stride = gridDim.x * blockDim.x;
    int i0 = blockIdx.x * blockDim.x + threadIdx.x;
    for (int i = i0; i < N_PTS * 3; i += stride) x_q[i] = qp[i];
    for (int i = i0; i < N_GRID * HD; i += stride) h_g[i] = codes[i];
    for (int i = i0; i < N_PTS * HD; i += stride) h_q[i] = 0.0f;
}

// ---------------- grid nodes: A = h@We1_top + be1 ; h_next = h + MLP(h, 0) ----------------
__global__ __launch_bounds__(128) void k_grid(
    const float* __restrict__ hg, float* __restrict__ Ag,
    const float* __restrict__ W1top, const float* __restrict__ b1,
    const float* __restrict__ Wn1top, const float* __restrict__ bn1,
    const float* __restrict__ Wn2, const float* __restrict__ bn2,
    int updateH, float* __restrict__ hg_out) {
    __shared__ float sh[8 * HD];
    __shared__ float st[8 * HD];
    int n0 = blockIdx.x * 8;
    int tid = threadIdx.x;
    for (int i = tid; i < 8 * HD; i += 128) sh[i] = hg[n0 * HD + i];
    __syncthreads();
    float acc[8];
    {
        float b = b1[tid];
#pragma unroll
        for (int e = 0; e < 8; e++) acc[e] = b;
        for (int j = 0; j < HD; j++) {
            float w = W1top[j * HD + tid];
#pragma unroll
            for (int e = 0; e < 8; e++) acc[e] += sh[e * HD + j] * w;
        }
#pragma unroll
        for (int e = 0; e < 8; e++) Ag[(n0 + e) * HD + tid] = acc[e];
    }
    if (updateH) {
        float b = bn1[tid];
#pragma unroll
        for (int e = 0; e < 8; e++) acc[e] = b;
        for (int j = 0; j < HD; j++) {
            float w = Wn1top[j * HD + tid];
#pragma unroll
            for (int e = 0; e < 8; e++) acc[e] += sh[e * HD + j] * w;
        }
#pragma unroll
        for (int e = 0; e < 8; e++) st[e * HD + tid] = silu_f(acc[e]);
        __syncthreads();
        b = bn2[tid];
#pragma unroll
        for (int e = 0; e < 8; e++) acc[e] = b;
        for (int j = 0; j < HD; j++) {
            float w = Wn2[j * HD + tid];
#pragma unroll
            for (int e = 0; e < 8; e++) acc[e] += st[e * HD + j] * w;
        }
#pragma unroll
        for (int e = 0; e < 8; e++) hg_out[(n0 + e) * HD + tid] = sh[e * HD + tid] + acc[e];
    }
}

// ---------------- fused per-query kernel: Bq GEMV + edges + x update + node MLP ----------------
__global__ __launch_bounds__(128) void k_mega(
    const float* __restrict__ Ag, float* __restrict__ hq, float* __restrict__ x_q,
    const float* __restrict__ W1mid, const float* __restrict__ wdrow,
    const float* __restrict__ W2, const float* __restrict__ b2v,
    const float* __restrict__ Wc, const float* __restrict__ cbp,
    const float* __restrict__ Wn1, const float* __restrict__ bn1,
    const float* __restrict__ Wn2, const float* __restrict__ bn2,
    const int* __restrict__ erow, const float* __restrict__ gridp,
    const float* __restrict__ qp, float* __restrict__ out,
    int outT, int isFinal) {
    __shared__ u16 sW[HD * HD];   // We2 as bf16 (32 KB)
    __shared__ float sh_h[HD];
    __shared__ float shm[HD];
    __shared__ float st[HD];
    __shared__ float sm[4 * HD];
    __shared__ float sred[2];
    int q = blockIdx.x;
    int tid = threadIdx.x;
    for (int i = tid; i < HD * HD; i += 128)
        sW[i] = (u16)__bfloat16_as_ushort(__float2bfloat16(W2[i]));
    float hv = hq[q * HD + tid];
    sh_h[tid] = hv;
    __syncthreads();
    // Bv = (h_q[q] @ We1_mid)[tid]
    float Bv = 0.0f;
#pragma unroll 4
    for (int j = 0; j < HD; j++) Bv += sh_h[j] * W1mid[j * HD + tid];
    float wd = wdrow[tid];
    float be2 = b2v[tid];
    float x0 = x_q[q * 3 + 0], x1 = x_q[q * 3 + 1], x2 = x_q[q * 3 + 2];
    float msum = 0.f, P0 = 0.f, P1 = 0.f, P2 = 0.f, D0 = 0.f, D1 = 0.f, D2 = 0.f;
    for (int grp = 0; grp < 4; ++grp) {
        float mreg[4], cmv[4], dxv[4], dyv[4], dzv[4];
#pragma unroll
        for (int e = 0; e < 4; e++) {
            int gnode = erow[q * DEG + grp * 4 + e] - N_PTS;
            int gl = gnode & (GPTS - 1);
            float r0 = gridp[gl * 3 + 0] - x0;
            float r1 = gridp[gl * 3 + 1] - x1;
            float r2 = gridp[gl * 3 + 2] - x2;
            float dist = sqrtf(r0 * r0 + r1 * r1 + r2 * r2);
            float inv = 1.0f / (dist + 1e-8f);
            dxv[e] = r0 * inv; dyv[e] = r1 * inv; dzv[e] = r2 * inv;
            float cw = 0.5f * (cosf(dist * 0.31415926535897931f) + 1.0f);
            cmv[e] = (dist <= 10.0f) ? cw : 0.0f;
            float pre = Ag[gnode * HD + tid] + Bv + dist * wd;
            mreg[e] = silu_f(pre);
        }
        __syncthreads();  // protect sm from previous grp's readers (covers sW/sh_h on grp 0)
        sm[tid * 4 + 0] = mreg[0];
        sm[tid * 4 + 1] = mreg[1];
        sm[tid * 4 + 2] = mreg[2];
        sm[tid * 4 + 3] = mreg[3];
        __syncthreads();
        float a0 = be2, a1 = be2, a2 = be2, a3 = be2;
#pragma unroll 8
        for (int j = 0; j < HD; j++) {
            float w = b2f(sW[j * HD + tid]);
            float4 m4 = *(const float4*)&sm[j * 4];
            a0 += m4.x * w; a1 += m4.y * w; a2 += m4.z * w; a3 += m4.w * w;
        }
        mreg[0] = a0; mreg[1] = a1; mreg[2] = a2; mreg[3] = a3;
#pragma unroll
        for (int e = 0; e < 4; e++) {
            float v = silu_f(mreg[e]) * cmv[e];
            msum += v;
            P0 += v * dxv[e]; P1 += v * dyv[e]; P2 += v * dzv[e];
            D0 += dxv[e]; D1 += dyv[e]; D2 += dzv[e];
        }
    }
    for (int t = 0; t < outT; t++) {
        float wc = isFinal ? Wc[tid * 5 + t] : Wc[tid];
        float sx = blockReduce128(P0 * wc, sred);
        float sy = blockReduce128(P1 * wc, sred);
        float sz = blockReduce128(P2 * wc, sred);
        if (tid == 0) {
            float cbv = cbp[t];
            float ddx = (sx + cbv * D0) * 0.0625f;
            float ddy = (sy + cbv * D1) * 0.0625f;
            float ddz = (sz + cbv * D2) * 0.0625f;
            if (isFinal) {
                out[q * 15 + t * 3 + 0] = x0 + ddx - qp[q * 3 + 0];
                out[q * 15 + t * 3 + 1] = x1 + ddy - qp[q * 3 + 1];
                out[q * 15 + t * 3 + 2] = x2 + ddz - qp[q * 3 + 2];
            } else {
                x_q[q * 3 + 0] = x0 + ddx;
                x_q[q * 3 + 1] = x1 + ddy;
                x_q[q * 3 + 2] = x2 + ddz;
            }
        }
    }
    if (!isFinal) {
        // fused node MLP: h_q[q] += silu([h, m_aggr] @ Wn1 + bn1) @ Wn2 + bn2
        shm[tid] = msum * 0.0625f;
        __syncthreads();
        float a = bn1[tid];
#pragma unroll 4
        for (int j = 0; j < HD; j++) a += sh_h[j] * Wn1[j * HD + tid];
#pragma unroll 4
        for (int j = 0; j < HD; j++) a += shm[j] * Wn1[(HD + j) * HD + tid];
        st[tid] = silu_f(a);
        __syncthreads();
        float o = bn2[tid];
#pragma unroll 4
        for (int j = 0; j < HD; j++) o += st[j] * Wn2[j * HD + tid];
        hq[q * HD + tid] = hv + o;
    }
}

extern "C" void kernel_launch(void* const* d_in, const int* in_sizes, int n_in,
                              void* d_out, int out_size, void* d_ws, size_t ws_size,
                              hipStream_t stream) {
    float* out = (float*)d_out;   // reference output dtype is float32
    int fill_blocks = (out_size + 255) / 256;

    static const int exp_sz[16] = { 49152, 524288, 1536, 131584, 512, 65536, 512, 384,
                                    3, 640, 5, 131072, 512, 65536, 512, 524288 };
    bool ok = (n_in == 16);
    for (int i = 0; ok && i < 16; i++) if (in_sizes[i] != exp_sz[i]) ok = false;
    if (!ok || ws_size < (size_t)20 * 1024 * 1024) {
        k_fillf<<<fill_blocks, 256, 0, stream>>>(out, 777.0f, out_size);
        return;
    }

    const float* qp    = (const float*)d_in[0];
    const float* codes = (const float*)d_in[1];
    const float* gridp = (const float*)d_in[2];
    const float* eW1   = (const float*)d_in[3];
    const float* eb1   = (const float*)d_in[4];
    const float* eW2   = (const float*)d_in[5];
    const float* eb2   = (const float*)d_in[6];
    const float* cW    = (const float*)d_in[7];
    const float* cb    = (const float*)d_in[8];
    const float* fcW   = (const float*)d_in[9];
    const float* fcb   = (const float*)d_in[10];
    const float* nW1   = (const float*)d_in[11];
    const float* nb1   = (const float*)d_in[12];
    const float* nW2   = (const float*)d_in[13];
    const float* nb2   = (const float*)d_in[14];
    const int*   erow  = (const int*)d_in[15];   // edge_index row 0 (grid side)

    float* ws = (float*)d_ws;
    float* x_q  = ws;  ws += N_PTS * 3;
    float* h_q  = ws;  ws += N_PTS * HD;
    float* hg_a = ws;  ws += N_GRID * HD;
    float* hg_b = ws;  ws += N_GRID * HD;
    float* A_g  = ws;  ws += N_GRID * HD;
    // ~12.8 MB of d_ws

    k_init<<<2048, 256, 0, stream>>>(qp, codes, x_q, hg_a, h_q);
    float* hg_cur = hg_a;
    float* hg_next = hg_b;
    for (int i = 0; i < 4; i++) {
        int fin = (i == 3);
        const float* W1l = eW1 + i * 257 * 128;
        k_grid<<<N_GRID / 8, 128, 0, stream>>>(hg_cur, A_g, W1l, eb1 + i * 128,
                                               nW1 + i * 256 * 128, nb1 + i * 128,
                                               nW2 + i * 16384, nb2 + i * 128,
                                               fin ? 0 : 1, hg_next);
        k_mega<<<N_PTS, 128, 0, stream>>>(A_g, h_q, x_q,
                                          W1l + 128 * 128, W1l + 256 * 128,
                                          eW2 + i * 16384, eb2 + i * 128,
                                          fin ? fcW : cW + i * 128, fin ? fcb : cb + i,
                                          nW1 + i * 256 * 128, nb1 + i * 128,
                                          nW2 + i * 16384, nb2 + i * 128,
                                          erow, gridp, qp, out, fin ? 5 : 1, fin);
        float* tmp = hg_cur; hg_cur = hg_next; hg_next = tmp;
    }
}

// Round 8
// 2282.148 us; speedup vs baseline: 1.1792x; 1.1792x over previous
//
#include <hip/hip_runtime.h>
#include <hip/hip_bf16.h>

typedef unsigned short u16;
typedef unsigned int u32;

#define N_PTS 16384
#define N_GRID 4096
#define GPTS 512
#define HD 128
#define DEG 16
#define QB 8

__device__ __forceinline__ float b2f(u16 u) { return __uint_as_float(((u32)u) << 16); }
__device__ __forceinline__ float silu_f(float x) { return x / (1.0f + __expf(-x)); }

__global__ void k_fillf(float* out, float v, int n) {
    int i = blockIdx.x * blockDim.x + threadIdx.x;
    if (i < n) out[i] = v;
}

// ---------------- init: x_q = qp, h_g = codes, h_q = 0 ----------------
__global__ void k_init(const float* __restrict__ qp, const float* __restrict__ codes,
                       float* __restrict__ x_q, float* __restrict__ h_g, float* __restrict__ h_q) {
    int stride = gridDim.x * blockDim.x;
    int i0 = blockIdx.x * blockDim.x + threadIdx.x;
    for (int i = i0; i < N_PTS * 3; i += stride) x_q[i] = qp[i];
    for (int i = i0; i < N_GRID * HD; i += stride) h_g[i] = codes[i];
    for (int i = i0; i < N_PTS * HD; i += stride) h_q[i] = 0.0f;
}

// ---------------- grid nodes: A = h@We1_top + be1 ; h_next = h + MLP(h, 0) ----------------
__global__ __launch_bounds__(128) void k_grid(
    const float* __restrict__ hg, float* __restrict__ Ag,
    const float* __restrict__ W1top, const float* __restrict__ b1,
    const float* __restrict__ Wn1top, const float* __restrict__ bn1,
    const float* __restrict__ Wn2, const float* __restrict__ bn2,
    int updateH, float* __restrict__ hg_out) {
    __shared__ float sh[8 * HD];
    __shared__ float st[8 * HD];
    int n0 = blockIdx.x * 8;
    int tid = threadIdx.x;
    for (int i = tid; i < 8 * HD; i += 128) sh[i] = hg[n0 * HD + i];
    __syncthreads();
    float acc[8];
    {
        float b = b1[tid];
#pragma unroll
        for (int e = 0; e < 8; e++) acc[e] = b;
        for (int j = 0; j < HD; j++) {
            float w = W1top[j * HD + tid];
#pragma unroll
            for (int e = 0; e < 8; e++) acc[e] += sh[e * HD + j] * w;
        }
#pragma unroll
        for (int e = 0; e < 8; e++) Ag[(n0 + e) * HD + tid] = acc[e];
    }
    if (updateH) {
        float b = bn1[tid];
#pragma unroll
        for (int e = 0; e < 8; e++) acc[e] = b;
        for (int j = 0; j < HD; j++) {
            float w = Wn1top[j * HD + tid];
#pragma unroll
            for (int e = 0; e < 8; e++) acc[e] += sh[e * HD + j] * w;
        }
#pragma unroll
        for (int e = 0; e < 8; e++) st[e * HD + tid] = silu_f(acc[e]);
        __syncthreads();
        b = bn2[tid];
#pragma unroll
        for (int e = 0; e < 8; e++) acc[e] = b;
        for (int j = 0; j < HD; j++) {
            float w = Wn2[j * HD + tid];
#pragma unroll
            for (int e = 0; e < 8; e++) acc[e] += st[e * HD + j] * w;
        }
#pragma unroll
        for (int e = 0; e < 8; e++) hg_out[(n0 + e) * HD + tid] = sh[e * HD + tid] + acc[e];
    }
}

// ---------------- fused 8-queries-per-block kernel ----------------
__global__ __launch_bounds__(128) void k_mega2(
    const float* __restrict__ Ag, float* __restrict__ hq, float* __restrict__ x_q,
    const float* __restrict__ W1mid, const float* __restrict__ wdrow,
    const float* __restrict__ W2, const float* __restrict__ b2v,
    const float* __restrict__ Wc, const float* __restrict__ cbp,
    const float* __restrict__ Wn1, const float* __restrict__ bn1,
    const float* __restrict__ Wn2, const float* __restrict__ bn2,
    const int* __restrict__ erow, const float* __restrict__ gridp,
    const float* __restrict__ qp, float* __restrict__ out,
    int outT, int isFinal) {
    __shared__ u16 sWt[HD * 132];        // We2 transposed col-major, padded: sWt[f*132+j] (33.8 KB)
    __shared__ float sm1[QB * HD];       // m1 row per edge-slot (reused as st in node MLP)
    __shared__ float shh[QB * HD];       // h_q rows
    __shared__ float smg[QB * HD];       // m_aggr rows
    __shared__ float sgeo[5 * 128];      // planes: dist,dx,dy,dz,cm per edge t
    __shared__ int sgi[128];             // grid-node index per edge t
    __shared__ float xs[QB * 3];
    __shared__ float sD[QB * 3];
    __shared__ float sp[2 * 40 * 3];     // per-wave partial reductions (outT<=5)

    int f = threadIdx.x;                 // feature 0..127
    int q0 = blockIdx.x * QB;
    int wid = f >> 6, lane = f & 63;

    // ---- stage We2 transposed (bf16) ----
    for (int k = f; k < HD * HD; k += 128) {
        int j = k >> 7, ff = k & 127;
        sWt[ff * 132 + j] = (u16)__bfloat16_as_ushort(__float2bfloat16(W2[k]));
    }
    // ---- stage h rows, x ----
#pragma unroll
    for (int q = 0; q < QB; q++) shh[q * HD + f] = hq[(q0 + q) * HD + f];
    if (f < QB * 3) xs[f] = x_q[q0 * 3 + f];
    __syncthreads();
    // ---- geometry: one edge per thread ----
    {
        int qq = f >> 4;
        int gi = erow[q0 * DEG + f] - N_PTS;
        sgi[f] = gi;
        int gl = gi & (GPTS - 1);
        float r0 = gridp[gl * 3 + 0] - xs[qq * 3 + 0];
        float r1 = gridp[gl * 3 + 1] - xs[qq * 3 + 1];
        float r2 = gridp[gl * 3 + 2] - xs[qq * 3 + 2];
        float dist = sqrtf(r0 * r0 + r1 * r1 + r2 * r2);
        float inv = 1.0f / (dist + 1e-8f);
        float cw = 0.5f * (__cosf(dist * 0.31415926535897931f) + 1.0f);
        sgeo[0 * 128 + f] = dist;
        sgeo[1 * 128 + f] = r0 * inv;
        sgeo[2 * 128 + f] = r1 * inv;
        sgeo[3 * 128 + f] = r2 * inv;
        sgeo[4 * 128 + f] = (dist <= 10.0f) ? cw : 0.0f;
    }
    float wd = wdrow[f];
    float be2 = b2v[f];
    // ---- Bv[q] = (h_q[q] @ We1_mid)[f] ----
    float bv[QB];
#pragma unroll
    for (int q = 0; q < QB; q++) bv[q] = 0.0f;
    __syncthreads();
#pragma unroll 4
    for (int j = 0; j < HD; j++) {
        float w = W1mid[j * HD + f];
#pragma unroll
        for (int q = 0; q < QB; q++) bv[q] += shh[q * HD + j] * w;
    }
    // ---- edge rounds: one edge per query per round ----
    float msum[QB], Px[QB], Py[QB], Pz[QB];
#pragma unroll
    for (int q = 0; q < QB; q++) { msum[q] = 0.f; Px[q] = 0.f; Py[q] = 0.f; Pz[q] = 0.f; }
    for (int r = 0; r < DEG; r++) {
        float m1v[QB];
#pragma unroll
        for (int q = 0; q < QB; q++) {
            int gi = sgi[q * DEG + r];
            float dist = sgeo[0 * 128 + q * DEG + r];
            float pre = Ag[gi * HD + f] + bv[q] + dist * wd;
            m1v[q] = silu_f(pre);
        }
        __syncthreads();   // previous round's GEMV reads done
#pragma unroll
        for (int q = 0; q < QB; q++) sm1[q * HD + f] = m1v[q];
        __syncthreads();   // sm1 ready
        float acc[QB];
#pragma unroll
        for (int q = 0; q < QB; q++) acc[q] = be2;
#pragma unroll 8
        for (int j4 = 0; j4 < 32; j4++) {
            ushort4 w4 = *(const ushort4*)&sWt[f * 132 + j4 * 4];
            float w0 = b2f(w4.x), w1 = b2f(w4.y), w2 = b2f(w4.z), w3 = b2f(w4.w);
#pragma unroll
            for (int q = 0; q < QB; q++) {
                float4 m4 = *(const float4*)&sm1[q * HD + j4 * 4];
                acc[q] += m4.x * w0 + m4.y * w1 + m4.z * w2 + m4.w * w3;
            }
        }
#pragma unroll
        for (int q = 0; q < QB; q++) {
            float cm = sgeo[4 * 128 + q * DEG + r];
            float v = silu_f(acc[q]) * cm;
            msum[q] += v;
            Px[q] += v * sgeo[1 * 128 + q * DEG + r];
            Py[q] += v * sgeo[2 * 128 + q * DEG + r];
            Pz[q] += v * sgeo[3 * 128 + q * DEG + r];
        }
    }
    // ---- D[q][c] = sum of dirs ----
    if (f < QB * 3) {
        int qq = f / 3, c = f % 3;
        float s = 0.f;
        for (int e = 0; e < DEG; e++) s += sgeo[(1 + c) * 128 + qq * DEG + e];
        sD[f] = s;
    }
    // ---- coordinate reductions ----
    for (int t = 0; t < outT; t++) {
        float wc = isFinal ? Wc[f * 5 + t] : Wc[f];
#pragma unroll
        for (int q = 0; q < QB; q++) {
            float vx = Px[q] * wc, vy = Py[q] * wc, vz = Pz[q] * wc;
#pragma unroll
            for (int o = 32; o > 0; o >>= 1) {
                vx += __shfl_down(vx, o, 64);
                vy += __shfl_down(vy, o, 64);
                vz += __shfl_down(vz, o, 64);
            }
            if (lane == 0) {
                int base = (wid * 40 + t * 8 + q) * 3;
                sp[base + 0] = vx; sp[base + 1] = vy; sp[base + 2] = vz;
            }
        }
    }
    // m_aggr rows for node MLP
#pragma unroll
    for (int q = 0; q < QB; q++) smg[q * HD + f] = msum[q] * 0.0625f;
    __syncthreads();
    if (f < outT * QB) {
        int t = f >> 3, q = f & 7;
        float cbv = cbp[t];
        int b0 = (t * 8 + q) * 3, b1 = (40 + t * 8 + q) * 3;
#pragma unroll
        for (int c = 0; c < 3; c++) {
            float dd = (sp[b0 + c] + sp[b1 + c] + cbv * sD[q * 3 + c]) * 0.0625f;
            if (isFinal)
                out[(q0 + q) * 15 + t * 3 + c] = xs[q * 3 + c] + dd - qp[(q0 + q) * 3 + c];
            else
                x_q[(q0 + q) * 3 + c] = xs[q * 3 + c] + dd;
        }
    }
    // ---- node MLP: h += silu([h, m_aggr]@Wn1 + bn1)@Wn2 + bn2 ----
    if (!isFinal) {
        float a[QB];
        float b = bn1[f];
#pragma unroll
        for (int q = 0; q < QB; q++) a[q] = b;
#pragma unroll 4
        for (int j = 0; j < HD; j++) {
            float w = Wn1[j * HD + f];
#pragma unroll
            for (int q = 0; q < QB; q++) a[q] += shh[q * HD + j] * w;
        }
#pragma unroll 4
        for (int j = 0; j < HD; j++) {
            float w = Wn1[(HD + j) * HD + f];
#pragma unroll
            for (int q = 0; q < QB; q++) a[q] += smg[q * HD + j] * w;
        }
        __syncthreads();   // sm1 (st) safe to overwrite
#pragma unroll
        for (int q = 0; q < QB; q++) sm1[q * HD + f] = silu_f(a[q]);
        __syncthreads();
        float o[QB];
        b = bn2[f];
#pragma unroll
        for (int q = 0; q < QB; q++) o[q] = b;
#pragma unroll 4
        for (int j = 0; j < HD; j++) {
            float w = Wn2[j * HD + f];
#pragma unroll
            for (int q = 0; q < QB; q++) o[q] += sm1[q * HD + j] * w;
        }
#pragma unroll
        for (int q = 0; q < QB; q++) hq[(q0 + q) * HD + f] = shh[q * HD + f] + o[q];
    }
}

extern "C" void kernel_launch(void* const* d_in, const int* in_sizes, int n_in,
                              void* d_out, int out_size, void* d_ws, size_t ws_size,
                              hipStream_t stream) {
    float* out = (float*)d_out;   // reference output dtype is float32
    int fill_blocks = (out_size + 255) / 256;

    static const int exp_sz[16] = { 49152, 524288, 1536, 131584, 512, 65536, 512, 384,
                                    3, 640, 5, 131072, 512, 65536, 512, 524288 };
    bool ok = (n_in == 16);
    for (int i = 0; ok && i < 16; i++) if (in_sizes[i] != exp_sz[i]) ok = false;
    if (!ok || ws_size < (size_t)20 * 1024 * 1024) {
        k_fillf<<<fill_blocks, 256, 0, stream>>>(out, 777.0f, out_size);
        return;
    }

    const float* qp    = (const float*)d_in[0];
    const float* codes = (const float*)d_in[1];
    const float* gridp = (const float*)d_in[2];
    const float* eW1   = (const float*)d_in[3];
    const float* eb1   = (const float*)d_in[4];
    const float* eW2   = (const float*)d_in[5];
    const float* eb2   = (const float*)d_in[6];
    const float* cW    = (const float*)d_in[7];
    const float* cb    = (const float*)d_in[8];
    const float* fcW   = (const float*)d_in[9];
    const float* fcb   = (const float*)d_in[10];
    const float* nW1   = (const float*)d_in[11];
    const float* nb1   = (const float*)d_in[12];
    const float* nW2   = (const float*)d_in[13];
    const float* nb2   = (const float*)d_in[14];
    const int*   erow  = (const int*)d_in[15];

    float* ws = (float*)d_ws;
    float* x_q  = ws;  ws += N_PTS * 3;
    float* h_q  = ws;  ws += N_PTS * HD;
    float* hg_a = ws;  ws += N_GRID * HD;
    float* hg_b = ws;  ws += N_GRID * HD;
    float* A_g  = ws;  ws += N_GRID * HD;

    k_init<<<2048, 256, 0, stream>>>(qp, codes, x_q, hg_a, h_q);
    float* hg_cur = hg_a;
    float* hg_next = hg_b;
    for (int i = 0; i < 4; i++) {
        int fin = (i == 3);
        const float* W1l = eW1 + i * 257 * 128;
        k_grid<<<N_GRID / 8, 128, 0, stream>>>(hg_cur, A_g, W1l, eb1 + i * 128,
                                               nW1 + i * 256 * 128, nb1 + i * 128,
                                               nW2 + i * 16384, nb2 + i * 128,
                                               fin ? 0 : 1, hg_next);
        k_mega2<<<N_PTS / QB, 128, 0, stream>>>(A_g, h_q, x_q,
                                                W1l + 128 * 128, W1l + 256 * 128,
                                                eW2 + i * 16384, eb2 + i * 128,
                                                fin ? fcW : cW + i * 128, fin ? fcb : cb + i,
                                                nW1 + i * 256 * 128, nb1 + i * 128,
                                                nW2 + i * 16384, nb2 + i * 128,
                                                erow, gridp, qp, out, fin ? 5 : 1, fin);
        float* tmp = hg_cur; hg_cur = hg_next; hg_next = tmp;
    }
}

// Round 9
// 1228.956 us; speedup vs baseline: 2.1897x; 1.8570x over previous
//
#include <hip/hip_runtime.h>
#include <hip/hip_bf16.h>

typedef unsigned short u16;
typedef unsigned int u32;
typedef __attribute__((ext_vector_type(8))) short short8;
typedef __attribute__((ext_vector_type(4))) float floatx4;

#define N_PTS 16384
#define N_GRID 4096
#define GPTS 512
#define HD 128
#define DEG 16
#define QB 16
#define EB 256

__device__ __forceinline__ float silu_f(float x) { return x / (1.0f + __expf(-x)); }
__device__ __forceinline__ short f2bf(float x) { return (short)__bfloat16_as_ushort(__float2bfloat16(x)); }

__global__ void k_fillf(float* out, float v, int n) {
    int i = blockIdx.x * blockDim.x + threadIdx.x;
    if (i < n) out[i] = v;
}

__global__ void k_init(const float* __restrict__ qp, const float* __restrict__ codes,
                       float* __restrict__ x_q, float* __restrict__ h_g, float* __restrict__ h_q) {
    int stride = gridDim.x * blockDim.x;
    int i0 = blockIdx.x * blockDim.x + threadIdx.x;
    for (int i = i0; i < N_PTS * 3; i += stride) x_q[i] = qp[i];
    for (int i = i0; i < N_GRID * HD; i += stride) h_g[i] = codes[i];
    for (int i = i0; i < N_PTS * HD; i += stride) h_q[i] = 0.0f;
}

// transpose We2 -> bf16 wsT[layer][f*128+k]
__global__ void k_prep(const float* __restrict__ eW2, short* __restrict__ wsT) {
    int idx = blockIdx.x * blockDim.x + threadIdx.x;
    if (idx >= 4 * HD * HD) return;
    int l = idx >> 14, rem = idx & 16383, f = rem >> 7, k = rem & 127;
    wsT[idx] = f2bf(eW2[l * 16384 + k * HD + f]);
}

// ---------------- grid nodes: A = h@We1_top + be1 ; h_next = h + MLP(h, 0) ----------------
__global__ __launch_bounds__(128) void k_grid(
    const float* __restrict__ hg, float* __restrict__ Ag,
    const float* __restrict__ W1top, const float* __restrict__ b1,
    const float* __restrict__ Wn1top, const float* __restrict__ bn1,
    const float* __restrict__ Wn2, const float* __restrict__ bn2,
    int updateH, float* __restrict__ hg_out) {
    __shared__ float sh[8 * HD];
    __shared__ float st[8 * HD];
    int n0 = blockIdx.x * 8;
    int tid = threadIdx.x;
    for (int i = tid; i < 8 * HD; i += 128) sh[i] = hg[n0 * HD + i];
    __syncthreads();
    float acc[8];
    {
        float b = b1[tid];
#pragma unroll
        for (int e = 0; e < 8; e++) acc[e] = b;
        for (int j = 0; j < HD; j++) {
            float w = W1top[j * HD + tid];
#pragma unroll
            for (int e = 0; e < 8; e++) acc[e] += sh[e * HD + j] * w;
        }
#pragma unroll
        for (int e = 0; e < 8; e++) Ag[(n0 + e) * HD + tid] = acc[e];
    }
    if (updateH) {
        float b = bn1[tid];
#pragma unroll
        for (int e = 0; e < 8; e++) acc[e] = b;
        for (int j = 0; j < HD; j++) {
            float w = Wn1top[j * HD + tid];
#pragma unroll
            for (int e = 0; e < 8; e++) acc[e] += sh[e * HD + j] * w;
        }
#pragma unroll
        for (int e = 0; e < 8; e++) st[e * HD + tid] = silu_f(acc[e]);
        __syncthreads();
        b = bn2[tid];
#pragma unroll
        for (int e = 0; e < 8; e++) acc[e] = b;
        for (int j = 0; j < HD; j++) {
            float w = Wn2[j * HD + tid];
#pragma unroll
            for (int e = 0; e < 8; e++) acc[e] += st[e * HD + j] * w;
        }
#pragma unroll
        for (int e = 0; e < 8; e++) hg_out[(n0 + e) * HD + tid] = sh[e * HD + tid] + acc[e];
    }
}

// ---------------- MFMA edge kernel: 16 queries (256 edges) per block, 256 threads ----------------
__global__ __launch_bounds__(256, 2) void k_mega3(
    const float* __restrict__ Ag, float* __restrict__ hq, float* __restrict__ x_q,
    const float* __restrict__ W1mid, const float* __restrict__ wdrow,
    const short* __restrict__ wsT, const float* __restrict__ b2v,
    const float* __restrict__ Wc, const float* __restrict__ cbp,
    const float* __restrict__ Wn1, const float* __restrict__ bn1,
    const float* __restrict__ Wn2, const float* __restrict__ bn2,
    const int* __restrict__ erow, const float* __restrict__ gridp,
    const float* __restrict__ qp, float* __restrict__ out,
    int outT, int isFinal) {
    __shared__ short sm1[EB * 72];     // bf16 m1 K-chunk, stride 72 (144B, aligned, conflict-free)
    __shared__ float shh[QB * HD];
    __shared__ float smg[QB * HD];
    __shared__ float sbv[QB * HD];
    __shared__ float sdist[EB];
    __shared__ float scm[EB];
    __shared__ float sdir[3 * EB];
    __shared__ int   sgi[EB];
    __shared__ float scoef[EB * 5];
    __shared__ float xs[QB * 3];

    int tid = threadIdx.x;
    int q0 = blockIdx.x * QB;
    int wid = tid >> 6, lane = tid & 63, quad = lane >> 4, c = lane & 15;

    for (int i = tid; i < QB * HD; i += 256) shh[i] = hq[q0 * HD + i];
    if (tid < QB * 3) xs[tid] = x_q[q0 * 3 + tid];
    __syncthreads();

    // geometry: one edge per thread
    {
        int e = tid, q = e >> 4;
        int gi = erow[q0 * DEG + e] - N_PTS;
        sgi[e] = gi;
        int gl = gi & (GPTS - 1);
        float r0 = gridp[gl * 3 + 0] - xs[q * 3 + 0];
        float r1 = gridp[gl * 3 + 1] - xs[q * 3 + 1];
        float r2 = gridp[gl * 3 + 2] - xs[q * 3 + 2];
        float dist = sqrtf(r0 * r0 + r1 * r1 + r2 * r2);
        float inv = 1.0f / (dist + 1e-8f);
        sdist[e] = dist;
        sdir[0 * EB + e] = r0 * inv;
        sdir[1 * EB + e] = r1 * inv;
        sdir[2 * EB + e] = r2 * inv;
        float cw = 0.5f * (__cosf(dist * 0.31415926535897931f) + 1.0f);
        scm[e] = (dist <= 10.0f) ? cw : 0.0f;
    }
    // Bq: sbv[q][f] = (h_q[q] @ We1_mid)[f]
    {
        int f = tid & 127, qh = tid >> 7;
        float b[8];
#pragma unroll
        for (int qq = 0; qq < 8; qq++) b[qq] = 0.f;
#pragma unroll 4
        for (int j = 0; j < HD; j++) {
            float w = W1mid[j * HD + f];
#pragma unroll
            for (int qq = 0; qq < 8; qq++) b[qq] += shh[(qh * 8 + qq) * HD + j] * w;
        }
#pragma unroll
        for (int qq = 0; qq < 8; qq++) sbv[(qh * 8 + qq) * HD + f] = b[qq];
    }
    __syncthreads();

    floatx4 acc[4][8];
#pragma unroll
    for (int mi = 0; mi < 4; mi++)
#pragma unroll
        for (int n = 0; n < 8; n++) acc[mi][n] = (floatx4)0.f;

    for (int ch = 0; ch < 2; ch++) {
        // m1 K-chunk: thread (k=tid&63, e = (tid>>6)+4i)
        {
            int kk = (tid & 63) + ch * 64;
            float wdv = wdrow[kk];
            int eb0 = tid >> 6;
#pragma unroll 4
            for (int i = 0; i < 64; i++) {
                int e = eb0 + i * 4;
                int q = e >> 4;
                float pre = Ag[sgi[e] * HD + kk] + sbv[q * HD + kk] + sdist[e] * wdv;
                sm1[e * 72 + (tid & 63)] = f2bf(silu_f(pre));
            }
        }
        __syncthreads();
        // A-frags: A[m=lane&15][k=quad*8+j]
        short8 afr[4][2];
#pragma unroll
        for (int mi = 0; mi < 4; mi++) {
            int e = (wid * 4 + mi) * 16 + c;
#pragma unroll
            for (int s = 0; s < 2; s++)
                afr[mi][s] = *(const short8*)&sm1[e * 72 + s * 32 + quad * 8];
        }
        // B-frags from global wsT[f][k]; MFMA
#pragma unroll
        for (int n = 0; n < 8; n++) {
            const short* bp = wsT + (n * 16 + c) * HD + ch * 64 + quad * 8;
            short8 bf0 = *(const short8*)(bp);
            short8 bf1 = *(const short8*)(bp + 32);
#pragma unroll
            for (int mi = 0; mi < 4; mi++) {
                acc[mi][n] = __builtin_amdgcn_mfma_f32_16x16x32_bf16(afr[mi][0], bf0, acc[mi][n], 0, 0, 0);
                acc[mi][n] = __builtin_amdgcn_mfma_f32_16x16x32_bf16(afr[mi][1], bf1, acc[mi][n], 0, 0, 0);
            }
        }
        __syncthreads();
    }

    // epilogue: v = silu(D + be2)*cm; m_aggr over rows; per-edge coef over cols
    for (int mi = 0; mi < 4; mi++) {
        int ebase = (wid * 4 + mi) * 16;
        float cmr[4];
#pragma unroll
        for (int r = 0; r < 4; r++) cmr[r] = scm[ebase + quad * 4 + r];
        float apc[4][5];
#pragma unroll
        for (int r = 0; r < 4; r++)
#pragma unroll
            for (int t = 0; t < 5; t++) apc[r][t] = 0.f;
#pragma unroll
        for (int n = 0; n < 8; n++) {
            int f = n * 16 + c;
            float be2v = b2v[f];
            float wcv[5];
            if (isFinal) {
#pragma unroll
                for (int t = 0; t < 5; t++) wcv[t] = Wc[f * 5 + t];
            } else {
                wcv[0] = Wc[f];
            }
            float cs = 0.f;
#pragma unroll
            for (int r = 0; r < 4; r++) {
                float v = silu_f(acc[mi][n][r] + be2v) * cmr[r];
                cs += v;
                for (int t = 0; t < outT; t++) apc[r][t] += v * wcv[t];
            }
            cs += __shfl_xor(cs, 16, 64);
            cs += __shfl_xor(cs, 32, 64);
            if (!isFinal && lane < 16) smg[(wid * 4 + mi) * HD + f] = cs * 0.0625f;
        }
        for (int t = 0; t < outT; t++) {
#pragma unroll
            for (int r = 0; r < 4; r++) {
                float v = apc[r][t];
                v += __shfl_xor(v, 1, 64);
                v += __shfl_xor(v, 2, 64);
                v += __shfl_xor(v, 4, 64);
                v += __shfl_xor(v, 8, 64);
                if (c == 0) scoef[(ebase + quad * 4 + r) * 5 + t] = v;
            }
        }
    }
    __syncthreads();

    // per-query coordinate update
    if (tid < QB * 3 * outT) {
        int q = tid / (3 * outT), rem = tid % (3 * outT), t = rem / 3, c2 = rem % 3;
        float cbv = cbp[t];
        float s = 0.f;
#pragma unroll 4
        for (int r = 0; r < 16; r++) {
            int e = q * 16 + r;
            s += (scoef[e * 5 + t] + cbv) * sdir[c2 * EB + e];
        }
        float dd = s * 0.0625f;
        if (isFinal) out[(q0 + q) * 15 + t * 3 + c2] = xs[q * 3 + c2] + dd - qp[(q0 + q) * 3 + c2];
        else x_q[(q0 + q) * 3 + c2] = xs[q * 3 + c2] + dd;
    }

    // node MLP: h += silu([h, m_aggr]@Wn1 + bn1)@Wn2 + bn2
    if (!isFinal) {
        float* stf = (float*)sm1;   // sm1 dead after MFMA barrier
        int f = tid & 127, qh = tid >> 7;
        float a[8];
        float bb = bn1[f];
#pragma unroll
        for (int qq = 0; qq < 8; qq++) a[qq] = bb;
#pragma unroll 2
        for (int j = 0; j < HD; j++) {
            float w = Wn1[j * HD + f];
#pragma unroll
            for (int qq = 0; qq < 8; qq++) a[qq] += shh[(qh * 8 + qq) * HD + j] * w;
        }
#pragma unroll 2
        for (int j = 0; j < HD; j++) {
            float w = Wn1[(HD + j) * HD + f];
#pragma unroll
            for (int qq = 0; qq < 8; qq++) a[qq] += smg[(qh * 8 + qq) * HD + j] * w;
        }
#pragma unroll
        for (int qq = 0; qq < 8; qq++) stf[(qh * 8 + qq) * HD + f] = silu_f(a[qq]);
        __syncthreads();
        float o[8];
        bb = bn2[f];
#pragma unroll
        for (int qq = 0; qq < 8; qq++) o[qq] = bb;
#pragma unroll 2
        for (int j = 0; j < HD; j++) {
            float w = Wn2[j * HD + f];
#pragma unroll
            for (int qq = 0; qq < 8; qq++) o[qq] += stf[(qh * 8 + qq) * HD + j] * w;
        }
#pragma unroll
        for (int qq = 0; qq < 8; qq++)
            hq[(q0 + qh * 8 + qq) * HD + f] = shh[(qh * 8 + qq) * HD + f] + o[qq];
    }
}

extern "C" void kernel_launch(void* const* d_in, const int* in_sizes, int n_in,
                              void* d_out, int out_size, void* d_ws, size_t ws_size,
                              hipStream_t stream) {
    float* out = (float*)d_out;
    int fill_blocks = (out_size + 255) / 256;

    static const int exp_sz[16] = { 49152, 524288, 1536, 131584, 512, 65536, 512, 384,
                                    3, 640, 5, 131072, 512, 65536, 512, 524288 };
    bool ok = (n_in == 16);
    for (int i = 0; ok && i < 16; i++) if (in_sizes[i] != exp_sz[i]) ok = false;
    if (!ok || ws_size < (size_t)20 * 1024 * 1024) {
        k_fillf<<<fill_blocks, 256, 0, stream>>>(out, 777.0f, out_size);
        return;
    }

    const float* qp    = (const float*)d_in[0];
    const float* codes = (const float*)d_in[1];
    const float* gridp = (const float*)d_in[2];
    const float* eW1   = (const float*)d_in[3];
    const float* eb1   = (const float*)d_in[4];
    const float* eW2   = (const float*)d_in[5];
    const float* eb2   = (const float*)d_in[6];
    const float* cW    = (const float*)d_in[7];
    const float* cb    = (const float*)d_in[8];
    const float* fcW   = (const float*)d_in[9];
    const float* fcb   = (const float*)d_in[10];
    const float* nW1   = (const float*)d_in[11];
    const float* nb1   = (const float*)d_in[12];
    const float* nW2   = (const float*)d_in[13];
    const float* nb2   = (const float*)d_in[14];
    const int*   erow  = (const int*)d_in[15];

    float* ws = (float*)d_ws;
    float* x_q  = ws;  ws += N_PTS * 3;
    float* h_q  = ws;  ws += N_PTS * HD;
    float* hg_a = ws;  ws += N_GRID * HD;
    float* hg_b = ws;  ws += N_GRID * HD;
    float* A_g  = ws;  ws += N_GRID * HD;
    short* wsT  = (short*)ws;   // 4 layers x 16384 bf16

    k_init<<<2048, 256, 0, stream>>>(qp, codes, x_q, hg_a, h_q);
    k_prep<<<(4 * HD * HD + 255) / 256, 256, 0, stream>>>(eW2, wsT);

    float* hg_cur = hg_a;
    float* hg_next = hg_b;
    for (int i = 0; i < 4; i++) {
        int fin = (i == 3);
        const float* W1l = eW1 + i * 257 * 128;
        k_grid<<<N_GRID / 8, 128, 0, stream>>>(hg_cur, A_g, W1l, eb1 + i * 128,
                                               nW1 + i * 256 * 128, nb1 + i * 128,
                                               nW2 + i * 16384, nb2 + i * 128,
                                               fin ? 0 : 1, hg_next);
        k_mega3<<<N_PTS / QB, 256, 0, stream>>>(A_g, h_q, x_q,
                                                W1l + 128 * 128, W1l + 256 * 128,
                                                wsT + i * 16384, eb2 + i * 128,
                                                fin ? fcW : cW + i * 128, fin ? fcb : cb + i,
                                                nW1 + i * 256 * 128, nb1 + i * 128,
                                                nW2 + i * 16384, nb2 + i * 128,
                                                erow, gridp, qp, out, fin ? 5 : 1, fin);
        float* tmp = hg_cur; hg_cur = hg_next; hg_next = tmp;
    }
}

// Round 10
// 743.985 us; speedup vs baseline: 3.6171x; 1.6519x over previous
//
#include <hip/hip_runtime.h>
#include <hip/hip_bf16.h>

typedef unsigned short u16;
typedef unsigned int u32;
typedef __attribute__((ext_vector_type(8))) short short8;
typedef __attribute__((ext_vector_type(4))) float floatx4;

#define N_PTS 16384
#define N_GRID 4096
#define GPTS 512
#define HD 128
#define DEG 16
#define QB 16
#define EB 256

__device__ __forceinline__ float silu_f(float x) { return x / (1.0f + __expf(-x)); }
__device__ __forceinline__ short f2bf(float x) { return (short)__bfloat16_as_ushort(__float2bfloat16(x)); }

__global__ void k_fillf(float* out, float v, int n) {
    int i = blockIdx.x * blockDim.x + threadIdx.x;
    if (i < n) out[i] = v;
}

__global__ void k_init(const float* __restrict__ qp, const float* __restrict__ codes,
                       float* __restrict__ x_q, float* __restrict__ h_g, float* __restrict__ h_q) {
    int stride = gridDim.x * blockDim.x;
    int i0 = blockIdx.x * blockDim.x + threadIdx.x;
    for (int i = i0; i < N_PTS * 3; i += stride) x_q[i] = qp[i];
    for (int i = i0; i < N_GRID * HD; i += stride) h_g[i] = codes[i];
    for (int i = i0; i < N_PTS * HD; i += stride) h_q[i] = 0.0f;
}

// transpose We2 -> bf16 wsT[layer][f*128+k]
__global__ void k_prep(const float* __restrict__ eW2, short* __restrict__ wsT) {
    int idx = blockIdx.x * blockDim.x + threadIdx.x;
    if (idx >= 4 * HD * HD) return;
    int l = idx >> 14, rem = idx & 16383, f = rem >> 7, k = rem & 127;
    wsT[idx] = f2bf(eW2[l * 16384 + k * HD + f]);
}

// ---------------- grid nodes: A = h@We1_top + be1 ; h_next = h + MLP(h, 0) ----------------
__global__ __launch_bounds__(128) void k_grid(
    const float* __restrict__ hg, float* __restrict__ Ag,
    const float* __restrict__ W1top, const float* __restrict__ b1,
    const float* __restrict__ Wn1top, const float* __restrict__ bn1,
    const float* __restrict__ Wn2, const float* __restrict__ bn2,
    int updateH, float* __restrict__ hg_out) {
    __shared__ float sh[8 * HD];
    __shared__ float st[8 * HD];
    int n0 = blockIdx.x * 8;
    int tid = threadIdx.x;
    for (int i = tid; i < 8 * HD; i += 128) sh[i] = hg[n0 * HD + i];
    __syncthreads();
    float acc[8];
    {
        float b = b1[tid];
#pragma unroll
        for (int e = 0; e < 8; e++) acc[e] = b;
        for (int j = 0; j < HD; j++) {
            float w = W1top[j * HD + tid];
#pragma unroll
            for (int e = 0; e < 8; e++) acc[e] += sh[e * HD + j] * w;
        }
#pragma unroll
        for (int e = 0; e < 8; e++) Ag[(n0 + e) * HD + tid] = acc[e];
    }
    if (updateH) {
        float b = bn1[tid];
#pragma unroll
        for (int e = 0; e < 8; e++) acc[e] = b;
        for (int j = 0; j < HD; j++) {
            float w = Wn1top[j * HD + tid];
#pragma unroll
            for (int e = 0; e < 8; e++) acc[e] += sh[e * HD + j] * w;
        }
#pragma unroll
        for (int e = 0; e < 8; e++) st[e * HD + tid] = silu_f(acc[e]);
        __syncthreads();
        b = bn2[tid];
#pragma unroll
        for (int e = 0; e < 8; e++) acc[e] = b;
        for (int j = 0; j < HD; j++) {
            float w = Wn2[j * HD + tid];
#pragma unroll
            for (int e = 0; e < 8; e++) acc[e] += st[e * HD + j] * w;
        }
#pragma unroll
        for (int e = 0; e < 8; e++) hg_out[(n0 + e) * HD + tid] = sh[e * HD + tid] + acc[e];
    }
}

// ---------------- MFMA edge kernel: 16 queries (256 edges) per block, 256 threads ----------------
// OUTT compile-time => all t-indexed arrays stay in registers (no scratch spill).
template <int OUTT, bool FIN>
__global__ __launch_bounds__(256, 2) void k_mega3(
    const float* __restrict__ Ag, float* __restrict__ hq, float* __restrict__ x_q,
    const float* __restrict__ W1mid, const float* __restrict__ wdrow,
    const short* __restrict__ wsT, const float* __restrict__ b2v,
    const float* __restrict__ Wc, const float* __restrict__ cbp,
    const float* __restrict__ Wn1, const float* __restrict__ bn1,
    const float* __restrict__ Wn2, const float* __restrict__ bn2,
    const int* __restrict__ erow, const float* __restrict__ gridp,
    const float* __restrict__ qp, float* __restrict__ out) {
    __shared__ short sm1[EB * 72];     // bf16 m1 K-chunk, stride 72 (conflict-free, 16B-aligned)
    __shared__ float shh[QB * HD];
    __shared__ float smg[QB * HD];
    __shared__ float sbv[QB * HD];
    __shared__ float sdist[EB];
    __shared__ float scm[EB];
    __shared__ float sdir[3 * EB];
    __shared__ int   sgi[EB];
    __shared__ float scoef[EB * OUTT];
    __shared__ float xs[QB * 3];

    int tid = threadIdx.x;
    int q0 = blockIdx.x * QB;
    int wid = tid >> 6, lane = tid & 63, quad = lane >> 4, c = lane & 15;

    for (int i = tid; i < QB * HD; i += 256) shh[i] = hq[q0 * HD + i];
    if (tid < QB * 3) xs[tid] = x_q[q0 * 3 + tid];
    __syncthreads();

    // geometry: one edge per thread
    {
        int e = tid, q = e >> 4;
        int gi = erow[q0 * DEG + e] - N_PTS;
        sgi[e] = gi;
        int gl = gi & (GPTS - 1);
        float r0 = gridp[gl * 3 + 0] - xs[q * 3 + 0];
        float r1 = gridp[gl * 3 + 1] - xs[q * 3 + 1];
        float r2 = gridp[gl * 3 + 2] - xs[q * 3 + 2];
        float dist = sqrtf(r0 * r0 + r1 * r1 + r2 * r2);
        float inv = 1.0f / (dist + 1e-8f);
        sdist[e] = dist;
        sdir[0 * EB + e] = r0 * inv;
        sdir[1 * EB + e] = r1 * inv;
        sdir[2 * EB + e] = r2 * inv;
        float cw = 0.5f * (__cosf(dist * 0.31415926535897931f) + 1.0f);
        scm[e] = (dist <= 10.0f) ? cw : 0.0f;
    }
    // Bq: sbv[q][f] = (h_q[q] @ We1_mid)[f]
    {
        int f = tid & 127, qh = tid >> 7;
        float b[8];
#pragma unroll
        for (int qq = 0; qq < 8; qq++) b[qq] = 0.f;
#pragma unroll 4
        for (int j = 0; j < HD; j++) {
            float w = W1mid[j * HD + f];
#pragma unroll
            for (int qq = 0; qq < 8; qq++) b[qq] += shh[(qh * 8 + qq) * HD + j] * w;
        }
#pragma unroll
        for (int qq = 0; qq < 8; qq++) sbv[(qh * 8 + qq) * HD + f] = b[qq];
    }
    __syncthreads();

    floatx4 acc[4][8];
#pragma unroll
    for (int mi = 0; mi < 4; mi++)
#pragma unroll
        for (int n = 0; n < 8; n++) acc[mi][n] = (floatx4)0.f;

    for (int ch = 0; ch < 2; ch++) {
        // m1 K-chunk: thread (k=tid&63, e = (tid>>6)+4i)
        {
            int kk = (tid & 63) + ch * 64;
            float wdv = wdrow[kk];
            int eb0 = tid >> 6;
#pragma unroll 4
            for (int i = 0; i < 64; i++) {
                int e = eb0 + i * 4;
                int q = e >> 4;
                float pre = Ag[sgi[e] * HD + kk] + sbv[q * HD + kk] + sdist[e] * wdv;
                sm1[e * 72 + (tid & 63)] = f2bf(silu_f(pre));
            }
        }
        __syncthreads();
        // A-frags: A[m=lane&15][k=quad*8+j]
        short8 afr[4][2];
#pragma unroll
        for (int mi = 0; mi < 4; mi++) {
            int e = (wid * 4 + mi) * 16 + c;
#pragma unroll
            for (int s = 0; s < 2; s++)
                afr[mi][s] = *(const short8*)&sm1[e * 72 + s * 32 + quad * 8];
        }
        // B-frags from global wsT[f][k]; MFMA
#pragma unroll
        for (int n = 0; n < 8; n++) {
            const short* bp = wsT + (n * 16 + c) * HD + ch * 64 + quad * 8;
            short8 bf0 = *(const short8*)(bp);
            short8 bf1 = *(const short8*)(bp + 32);
#pragma unroll
            for (int mi = 0; mi < 4; mi++) {
                acc[mi][n] = __builtin_amdgcn_mfma_f32_16x16x32_bf16(afr[mi][0], bf0, acc[mi][n], 0, 0, 0);
                acc[mi][n] = __builtin_amdgcn_mfma_f32_16x16x32_bf16(afr[mi][1], bf1, acc[mi][n], 0, 0, 0);
            }
        }
        __syncthreads();
    }

    // epilogue: v = silu(D + be2)*cm; m_aggr over rows; per-edge coef over cols
#pragma unroll
    for (int mi = 0; mi < 4; mi++) {
        int ebase = (wid * 4 + mi) * 16;
        float cmr[4];
#pragma unroll
        for (int r = 0; r < 4; r++) cmr[r] = scm[ebase + quad * 4 + r];
        float apc[4][OUTT];
#pragma unroll
        for (int r = 0; r < 4; r++)
#pragma unroll
            for (int t = 0; t < OUTT; t++) apc[r][t] = 0.f;
#pragma unroll
        for (int n = 0; n < 8; n++) {
            int f = n * 16 + c;
            float be2v = b2v[f];
            float wcv[OUTT];
            if (FIN) {
#pragma unroll
                for (int t = 0; t < OUTT; t++) wcv[t] = Wc[f * 5 + t];
            } else {
                wcv[0] = Wc[f];
            }
            float cs = 0.f;
#pragma unroll
            for (int r = 0; r < 4; r++) {
                float v = silu_f(acc[mi][n][r] + be2v) * cmr[r];
                cs += v;
#pragma unroll
                for (int t = 0; t < OUTT; t++) apc[r][t] += v * wcv[t];
            }
            cs += __shfl_xor(cs, 16, 64);
            cs += __shfl_xor(cs, 32, 64);
            if (!FIN && lane < 16) smg[(wid * 4 + mi) * HD + f] = cs * 0.0625f;
        }
#pragma unroll
        for (int t = 0; t < OUTT; t++) {
#pragma unroll
            for (int r = 0; r < 4; r++) {
                float v = apc[r][t];
                v += __shfl_xor(v, 1, 64);
                v += __shfl_xor(v, 2, 64);
                v += __shfl_xor(v, 4, 64);
                v += __shfl_xor(v, 8, 64);
                if (c == 0) scoef[(ebase + quad * 4 + r) * OUTT + t] = v;
            }
        }
    }
    __syncthreads();

    // per-query coordinate update
    if (tid < QB * 3 * OUTT) {
        int q = tid / (3 * OUTT), rem = tid % (3 * OUTT), t = rem / 3, c2 = rem % 3;
        float cbv = cbp[t];
        float s = 0.f;
#pragma unroll 4
        for (int r = 0; r < 16; r++) {
            int e = q * 16 + r;
            s += (scoef[e * OUTT + t] + cbv) * sdir[c2 * EB + e];
        }
        float dd = s * 0.0625f;
        if (FIN) out[(q0 + q) * 15 + t * 3 + c2] = xs[q * 3 + c2] + dd - qp[(q0 + q) * 3 + c2];
        else x_q[(q0 + q) * 3 + c2] = xs[q * 3 + c2] + dd;
    }

    // node MLP: h += silu([h, m_aggr]@Wn1 + bn1)@Wn2 + bn2
    if (!FIN) {
        float* stf = (float*)sm1;   // sm1 dead after MFMA barrier
        int f = tid & 127, qh = tid >> 7;
        float a[8];
        float bb = bn1[f];
#pragma unroll
        for (int qq = 0; qq < 8; qq++) a[qq] = bb;
#pragma unroll 2
        for (int j = 0; j < HD; j++) {
            float w = Wn1[j * HD + f];
#pragma unroll
            for (int qq = 0; qq < 8; qq++) a[qq] += shh[(qh * 8 + qq) * HD + j] * w;
        }
#pragma unroll 2
        for (int j = 0; j < HD; j++) {
            float w = Wn1[(HD + j) * HD + f];
#pragma unroll
            for (int qq = 0; qq < 8; qq++) a[qq] += smg[(qh * 8 + qq) * HD + j] * w;
        }
#pragma unroll
        for (int qq = 0; qq < 8; qq++) stf[(qh * 8 + qq) * HD + f] = silu_f(a[qq]);
        __syncthreads();
        float o[8];
        bb = bn2[f];
#pragma unroll
        for (int qq = 0; qq < 8; qq++) o[qq] = bb;
#pragma unroll 2
        for (int j = 0; j < HD; j++) {
            float w = Wn2[j * HD + f];
#pragma unroll
            for (int qq = 0; qq < 8; qq++) o[qq] += stf[(qh * 8 + qq) * HD + j] * w;
        }
#pragma unroll
        for (int qq = 0; qq < 8; qq++)
            hq[(q0 + qh * 8 + qq) * HD + f] = shh[(qh * 8 + qq) * HD + f] + o[qq];
    }
}

extern "C" void kernel_launch(void* const* d_in, const int* in_sizes, int n_in,
                              void* d_out, int out_size, void* d_ws, size_t ws_size,
                              hipStream_t stream) {
    float* out = (float*)d_out;
    int fill_blocks = (out_size + 255) / 256;

    static const int exp_sz[16] = { 49152, 524288, 1536, 131584, 512, 65536, 512, 384,
                                    3, 640, 5, 131072, 512, 65536, 512, 524288 };
    bool ok = (n_in == 16);
    for (int i = 0; ok && i < 16; i++) if (in_sizes[i] != exp_sz[i]) ok = false;
    if (!ok || ws_size < (size_t)20 * 1024 * 1024) {
        k_fillf<<<fill_blocks, 256, 0, stream>>>(out, 777.0f, out_size);
        return;
    }

    const float* qp    = (const float*)d_in[0];
    const float* codes = (const float*)d_in[1];
    const float* gridp = (const float*)d_in[2];
    const float* eW1   = (const float*)d_in[3];
    const float* eb1   = (const float*)d_in[4];
    const float* eW2   = (const float*)d_in[5];
    const float* eb2   = (const float*)d_in[6];
    const float* cW    = (const float*)d_in[7];
    const float* cb    = (const float*)d_in[8];
    const float* fcW   = (const float*)d_in[9];
    const float* fcb   = (const float*)d_in[10];
    const float* nW1   = (const float*)d_in[11];
    const float* nb1   = (const float*)d_in[12];
    const float* nW2   = (const float*)d_in[13];
    const float* nb2   = (const float*)d_in[14];
    const int*   erow  = (const int*)d_in[15];

    float* ws = (float*)d_ws;
    float* x_q  = ws;  ws += N_PTS * 3;
    float* h_q  = ws;  ws += N_PTS * HD;
    float* hg_a = ws;  ws += N_GRID * HD;
    float* hg_b = ws;  ws += N_GRID * HD;
    float* A_g  = ws;  ws += N_GRID * HD;
    short* wsT  = (short*)ws;   // 4 layers x 16384 bf16

    k_init<<<2048, 256, 0, stream>>>(qp, codes, x_q, hg_a, h_q);
    k_prep<<<(4 * HD * HD + 255) / 256, 256, 0, stream>>>(eW2, wsT);

    float* hg_cur = hg_a;
    float* hg_next = hg_b;
    for (int i = 0; i < 4; i++) {
        int fin = (i == 3);
        const float* W1l = eW1 + i * 257 * 128;
        k_grid<<<N_GRID / 8, 128, 0, stream>>>(hg_cur, A_g, W1l, eb1 + i * 128,
                                               nW1 + i * 256 * 128, nb1 + i * 128,
                                               nW2 + i * 16384, nb2 + i * 128,
                                               fin ? 0 : 1, hg_next);
        if (!fin)
            k_mega3<1, false><<<N_PTS / QB, 256, 0, stream>>>(A_g, h_q, x_q,
                W1l + 128 * 128, W1l + 256 * 128, wsT + i * 16384, eb2 + i * 128,
                cW + i * 128, cb + i, nW1 + i * 256 * 128, nb1 + i * 128,
                nW2 + i * 16384, nb2 + i * 128, erow, gridp, qp, out);
        else
            k_mega3<5, true><<<N_PTS / QB, 256, 0, stream>>>(A_g, h_q, x_q,
                W1l + 128 * 128, W1l + 256 * 128, wsT + i * 16384, eb2 + i * 128,
                fcW, fcb, nW1 + i * 256 * 128, nb1 + i * 128,
                nW2 + i * 16384, nb2 + i * 128, erow, gridp, qp, out);
        float* tmp = hg_cur; hg_cur = hg_next; hg_next = tmp;
    }
}